// Round 1
// baseline (578.227 us; speedup 1.0000x reference)
//
#include <hip/hip_runtime.h>

#define CS   1024
#define CZ   128

typedef __attribute__((ext_vector_type(8))) short short8;
typedef __attribute__((ext_vector_type(4))) float floatx4;

static __device__ __forceinline__ unsigned short f2bf(float f) {
  unsigned int u = __float_as_uint(f);
  u = (u + 0x7fffu + ((u >> 16) & 1u)) >> 16;   // round-to-nearest-even
  return (unsigned short)u;
}

// ---------------- Kernel 1: LayerNorm + proj -> q (bf16); expand W_i (bf16), c_i (f32) ----------------
// W_all[i][z][d] = bf16(k[i,d]*ow[z,d] + ow[z,32+d])      (8 MB)
// c_all[i][z]    = ob[z] - sum_d k[i,d]*ow[z,32+d]        (512 KB)
__global__ __launch_bounds__(256) void prep_kernel(
    const float* __restrict__ seq,
    const float* __restrict__ lnw,
    const float* __restrict__ lnb,
    const float* __restrict__ pw,
    const float* __restrict__ pb,
    const float* __restrict__ ow,
    const float* __restrict__ ob,
    unsigned short* __restrict__ q_ws,
    unsigned short* __restrict__ w_all,
    float* __restrict__ c_all) {
  const int row  = blockIdx.x;
  const int tid  = threadIdx.x;
  const int lane = tid & 63;
  const int wave = tid >> 6;

  __shared__ __align__(16) float snf[CS];
  __shared__ float sred[8];
  __shared__ float pacc[4][64];
  __shared__ float ksh[32];

  // each thread owns 4 consecutive elements
  float4 v = *(const float4*)(seq + (size_t)row * CS + tid * 4);
  float s  = v.x + v.y + v.z + v.w;
  float ss = v.x * v.x + v.y * v.y + v.z * v.z + v.w * v.w;
  #pragma unroll
  for (int off = 32; off >= 1; off >>= 1) {
    s  += __shfl_down(s, off, 64);
    ss += __shfl_down(ss, off, 64);
  }
  if (lane == 0) { sred[wave] = s; sred[4 + wave] = ss; }
  __syncthreads();
  const float mu   = (sred[0] + sred[1] + sred[2] + sred[3]) * (1.0f / CS);
  const float var  = (sred[4] + sred[5] + sred[6] + sred[7]) * (1.0f / CS) - mu * mu;
  const float rstd = rsqrtf(var + 1e-5f);
  {
    const int c = tid * 4;
    float4 gw = *(const float4*)(lnw + c);
    float4 gb = *(const float4*)(lnb + c);
    snf[c + 0] = (v.x - mu) * rstd * gw.x + gb.x;
    snf[c + 1] = (v.y - mu) * rstd * gw.y + gb.y;
    snf[c + 2] = (v.z - mu) * rstd * gw.z + gb.z;
    snf[c + 3] = (v.w - mu) * rstd * gw.w + gb.w;
  }
  __syncthreads();

  // proj: wave w handles quarter-range w of the K dim, lane = output dim d (0..63)
  const int d    = tid & 63;
  const int part = wave;
  const float* pwr = pw + (size_t)d * CS + part * 256;
  const float* snr = snf + part * 256;
  float acc = 0.f;
  #pragma unroll 4
  for (int kk = 0; kk < 32; ++kk) {
    float4 a0 = *(const float4*)(snr + kk * 8);
    float4 a1 = *(const float4*)(snr + kk * 8 + 4);
    float4 b0 = *(const float4*)(pwr + kk * 8);
    float4 b1 = *(const float4*)(pwr + kk * 8 + 4);
    acc += a0.x * b0.x + a0.y * b0.y + a0.z * b0.z + a0.w * b0.w
         + a1.x * b1.x + a1.y * b1.y + a1.z * b1.z + a1.w * b1.w;
  }
  pacc[part][d] = acc;
  __syncthreads();
  if (tid < 64) {
    float r = pacc[0][tid] + pacc[1][tid] + pacc[2][tid] + pacc[3][tid] + pb[tid];
    if (tid < 32) q_ws[row * 32 + tid] = f2bf(r);
    else          ksh[tid - 32] = r;
  }
  __syncthreads();

  // ---- expand W_i and c_i (thread: z = tid>>1, half of d-range) ----
  const int z  = tid >> 1;
  const int dh = (tid & 1) << 4;
  const float* owr = ow + z * 64;
  unsigned short wloc[16];
  #pragma unroll
  for (int t4 = 0; t4 < 4; ++t4) {
    const int dd = dh + t4 * 4;
    float4 a = *(const float4*)(owr + dd);
    float4 b = *(const float4*)(owr + 32 + dd);
    wloc[t4 * 4 + 0] = f2bf(ksh[dd + 0] * a.x + b.x);
    wloc[t4 * 4 + 1] = f2bf(ksh[dd + 1] * a.y + b.y);
    wloc[t4 * 4 + 2] = f2bf(ksh[dd + 2] * a.z + b.z);
    wloc[t4 * 4 + 3] = f2bf(ksh[dd + 3] * a.w + b.w);
  }
  unsigned short* wdst = w_all + (size_t)row * 4096 + tid * 16;   // [row][z][d], d contiguous
  *(uint4*)(wdst)     = *(const uint4*)(wloc);
  *(uint4*)(wdst + 8) = *(const uint4*)(wloc + 8);

  if ((tid & 1) == 0) {
    float c = ob[z];
    #pragma unroll
    for (int t4 = 0; t4 < 8; ++t4) {
      const int dd = t4 * 4;
      float4 b = *(const float4*)(owr + 32 + dd);
      c -= ksh[dd + 0] * b.x + ksh[dd + 1] * b.y + ksh[dd + 2] * b.z + ksh[dd + 3] * b.w;
    }
    c_all[row * CZ + z] = c;
  }
}

// ---------------- Kernel 2: out[i,j,z] = q[j,:] . W_i[z,:] + c_i[z] ----------------
// MFMA with A = W_i (M = z), B = q (N = j)  =>  each lane's 4 acc regs are 4
// CONSECUTIVE z values at one j  =>  global_store_dwordx4 per (lane, zt).
// No LDS, no per-block W rebuild: all fragments load coalesced from global.
__global__ __launch_bounds__(256, 3) void pair_kernel(
    const unsigned short* __restrict__ q_ws,
    const unsigned short* __restrict__ w_all,
    const float* __restrict__ c_all,
    float* __restrict__ out) {
  const int bid  = blockIdx.x;
  const int i    = bid >> 2;     // k-row index
  const int jt   = bid & 3;      // 256-wide j tile
  const int tid  = threadIdx.x;
  const int lane = tid & 63;
  const int wave = tid >> 6;
  const int quad = lane >> 4;
  const int n16  = lane & 15;

  // W fragments: wf[zt] holds A[m = z%16][k = quad*8 + e] for z = zt*16 + n16
  const unsigned short* wbase = w_all + (size_t)i * 4096 + n16 * 32 + quad * 8;
  short8 wf[8];
  #pragma unroll
  for (int zt = 0; zt < 8; ++zt) wf[zt] = *(const short8*)(wbase + zt * 512);

  // c fragments: cv[zt] = c_i[zt*16 + quad*4 .. +3]  (matches D-row layout)
  const float* cbase = c_all + i * CZ + quad * 4;
  floatx4 cv[8];
  #pragma unroll
  for (int zt = 0; zt < 8; ++zt) {
    float4 t = *(const float4*)(cbase + zt * 16);
    floatx4 c4; c4[0] = t.x; c4[1] = t.y; c4[2] = t.z; c4[3] = t.w;
    cv[zt] = c4;
  }

  const int jbase = jt * 256 + wave * 64;
  #pragma unroll
  for (int js = 0; js < 4; ++js) {
    const int j = jbase + js * 16 + n16;
    // B-frag: B[n = j%16][k = quad*8 + e] -- coalesced 16 B/lane
    short8 qf = *(const short8*)(q_ws + j * 32 + quad * 8);
    float* obase = out + (size_t)(i * 1024 + j) * CZ + quad * 4;
    #pragma unroll
    for (int zt = 0; zt < 8; ++zt) {
      floatx4 acc = cv[zt];   // fold +c_i[z] into accumulator
      acc = __builtin_amdgcn_mfma_f32_16x16x32_bf16(wf[zt], qf, acc, 0, 0, 0);
      // D: row(z) = quad*4 + r (consecutive z!), col(j) = n16
      *(floatx4*)(obase + zt * 16) = acc;   // 16 B/lane, 64 B per 4-lane group
    }
  }
}

extern "C" void kernel_launch(void* const* d_in, const int* in_sizes, int n_in,
                              void* d_out, int out_size, void* d_ws, size_t ws_size,
                              hipStream_t stream) {
  const float* seq = (const float*)d_in[0];
  const float* lnw = (const float*)d_in[1];
  const float* lnb = (const float*)d_in[2];
  const float* pw  = (const float*)d_in[3];
  const float* pb  = (const float*)d_in[4];
  const float* ow  = (const float*)d_in[5];
  const float* ob  = (const float*)d_in[6];
  float* out = (float*)d_out;

  unsigned short* q_ws  = (unsigned short*)d_ws;                         // 1024*32 bf16  = 64 KB
  float*          c_all = (float*)((char*)d_ws + 64 * 1024);             // 1024*128 f32  = 512 KB
  unsigned short* w_all = (unsigned short*)((char*)d_ws + 640 * 1024);   // 1024*128*32 bf16 = 8 MB

  prep_kernel<<<1024, 256, 0, stream>>>(seq, lnw, lnb, pw, pb, ow, ob, q_ws, w_all, c_all);
  pair_kernel<<<4096, 256, 0, stream>>>(q_ws, w_all, c_all, out);
}

// Round 2
// 565.831 us; speedup vs baseline: 1.0219x; 1.0219x over previous
//
#include <hip/hip_runtime.h>

#define CS   1024
#define CZ   128

typedef __attribute__((ext_vector_type(8))) short short8;
typedef __attribute__((ext_vector_type(4))) float floatx4;

static __device__ __forceinline__ unsigned short f2bf(float f) {
  unsigned int u = __float_as_uint(f);
  u = (u + 0x7fffu + ((u >> 16) & 1u)) >> 16;   // round-to-nearest-even
  return (unsigned short)u;
}

// ---------------- Kernel 1: LayerNorm + proj -> q (bf16); expand W_i (bf16), c_i (f32) ----------------
// W_all[i][z][d] = bf16(k[i,d]*ow[z,d] + ow[z,32+d])      (8 MB)
// c_all[i][z]    = ob[z] - sum_d k[i,d]*ow[z,32+d]        (512 KB)
__global__ __launch_bounds__(256) void prep_kernel(
    const float* __restrict__ seq,
    const float* __restrict__ lnw,
    const float* __restrict__ lnb,
    const float* __restrict__ pw,
    const float* __restrict__ pb,
    const float* __restrict__ ow,
    const float* __restrict__ ob,
    unsigned short* __restrict__ q_ws,
    unsigned short* __restrict__ w_all,
    float* __restrict__ c_all) {
  const int row  = blockIdx.x;
  const int tid  = threadIdx.x;
  const int lane = tid & 63;
  const int wave = tid >> 6;

  __shared__ __align__(16) float snf[CS];
  __shared__ float sred[8];
  __shared__ float pacc[4][64];
  __shared__ float ksh[32];

  // each thread owns 4 consecutive elements
  float4 v = *(const float4*)(seq + (size_t)row * CS + tid * 4);
  float s  = v.x + v.y + v.z + v.w;
  float ss = v.x * v.x + v.y * v.y + v.z * v.z + v.w * v.w;
  #pragma unroll
  for (int off = 32; off >= 1; off >>= 1) {
    s  += __shfl_down(s, off, 64);
    ss += __shfl_down(ss, off, 64);
  }
  if (lane == 0) { sred[wave] = s; sred[4 + wave] = ss; }
  __syncthreads();
  const float mu   = (sred[0] + sred[1] + sred[2] + sred[3]) * (1.0f / CS);
  const float var  = (sred[4] + sred[5] + sred[6] + sred[7]) * (1.0f / CS) - mu * mu;
  const float rstd = rsqrtf(var + 1e-5f);
  {
    const int c = tid * 4;
    float4 gw = *(const float4*)(lnw + c);
    float4 gb = *(const float4*)(lnb + c);
    snf[c + 0] = (v.x - mu) * rstd * gw.x + gb.x;
    snf[c + 1] = (v.y - mu) * rstd * gw.y + gb.y;
    snf[c + 2] = (v.z - mu) * rstd * gw.z + gb.z;
    snf[c + 3] = (v.w - mu) * rstd * gw.w + gb.w;
  }
  __syncthreads();

  // proj: wave w handles quarter-range w of the K dim, lane = output dim d (0..63)
  const int d    = tid & 63;
  const int part = wave;
  const float* pwr = pw + (size_t)d * CS + part * 256;
  const float* snr = snf + part * 256;
  float acc = 0.f;
  #pragma unroll 4
  for (int kk = 0; kk < 32; ++kk) {
    float4 a0 = *(const float4*)(snr + kk * 8);
    float4 a1 = *(const float4*)(snr + kk * 8 + 4);
    float4 b0 = *(const float4*)(pwr + kk * 8);
    float4 b1 = *(const float4*)(pwr + kk * 8 + 4);
    acc += a0.x * b0.x + a0.y * b0.y + a0.z * b0.z + a0.w * b0.w
         + a1.x * b1.x + a1.y * b1.y + a1.z * b1.z + a1.w * b1.w;
  }
  pacc[part][d] = acc;
  __syncthreads();
  if (tid < 64) {
    float r = pacc[0][tid] + pacc[1][tid] + pacc[2][tid] + pacc[3][tid] + pb[tid];
    if (tid < 32) q_ws[row * 32 + tid] = f2bf(r);
    else          ksh[tid - 32] = r;
  }
  __syncthreads();

  // ---- expand W_i and c_i (thread: z = tid>>1, half of d-range) ----
  const int z  = tid >> 1;
  const int dh = (tid & 1) << 4;
  const float* owr = ow + z * 64;
  unsigned short wloc[16];
  #pragma unroll
  for (int t4 = 0; t4 < 4; ++t4) {
    const int dd = dh + t4 * 4;
    float4 a = *(const float4*)(owr + dd);
    float4 b = *(const float4*)(owr + 32 + dd);
    wloc[t4 * 4 + 0] = f2bf(ksh[dd + 0] * a.x + b.x);
    wloc[t4 * 4 + 1] = f2bf(ksh[dd + 1] * a.y + b.y);
    wloc[t4 * 4 + 2] = f2bf(ksh[dd + 2] * a.z + b.z);
    wloc[t4 * 4 + 3] = f2bf(ksh[dd + 3] * a.w + b.w);
  }
  unsigned short* wdst = w_all + (size_t)row * 4096 + tid * 16;   // [row][z][d], d contiguous
  *(uint4*)(wdst)     = *(const uint4*)(wloc);
  *(uint4*)(wdst + 8) = *(const uint4*)(wloc + 8);

  if ((tid & 1) == 0) {
    float c = ob[z];
    #pragma unroll
    for (int t4 = 0; t4 < 8; ++t4) {
      const int dd = t4 * 4;
      float4 b = *(const float4*)(owr + 32 + dd);
      c -= ksh[dd + 0] * b.x + ksh[dd + 1] * b.y + ksh[dd + 2] * b.z + ksh[dd + 3] * b.w;
    }
    c_all[row * CZ + z] = c;
  }
}

// ---------------- Kernel 2: out[i,j,z] = q[j,:] . W_i[z,:] + c_i[z] ----------------
// MFMA (A = W_i: M = z, B = q: N = j), then a per-wave LDS transpose so every
// global store instruction is a fully contiguous 1 KiB (64 lanes x dwordx4).
// Partial-line (64B-segment) stores were read-allocating ~512 MB from HBM;
// full-line streaming writes skip the allocate-read (proved by the fill
// kernel's FETCH_SIZE ~= 0 for 2 GiB written).
__global__ __launch_bounds__(256, 3) void pair_kernel(
    const unsigned short* __restrict__ q_ws,
    const unsigned short* __restrict__ w_all,
    const float* __restrict__ c_all,
    float* __restrict__ out) {
  const int bid  = blockIdx.x;
  const int i    = bid >> 2;     // k-row index
  const int jt   = bid & 3;      // 256-wide j tile
  const int tid  = threadIdx.x;
  const int lane = tid & 63;
  const int wave = tid >> 6;
  const int quad = lane >> 4;
  const int n16  = lane & 15;

  // Per-wave transpose tile: 16 j-rows x 128 z, stride 132 floats.
  // stride/4 = 33 === 1 (mod 8)  =>  both ds_write and ds_read patterns hit
  // each 4-bank group with exactly 8 lanes -> conflict-free b128 access.
  __shared__ __align__(16) float tsh[4][16 * 132];

  // W fragments: wf[zt] holds A[m = z%16][k = quad*8 + e] for z = zt*16 + n16
  const unsigned short* wbase = w_all + (size_t)i * 4096 + n16 * 32 + quad * 8;
  short8 wf[8];
  #pragma unroll
  for (int zt = 0; zt < 8; ++zt) wf[zt] = *(const short8*)(wbase + zt * 512);

  // c fragments: cv[zt] = c_i[zt*16 + quad*4 .. +3]  (matches D-row layout)
  const float* cbase = c_all + i * CZ + quad * 4;
  floatx4 cv[8];
  #pragma unroll
  for (int zt = 0; zt < 8; ++zt) {
    float4 t = *(const float4*)(cbase + zt * 16);
    floatx4 c4; c4[0] = t.x; c4[1] = t.y; c4[2] = t.z; c4[3] = t.w;
    cv[zt] = c4;
  }

  float* twave = &tsh[wave][0];
  const int jbase = jt * 256 + wave * 64;

  #pragma unroll
  for (int js = 0; js < 4; ++js) {
    // B-frag: B[n = j%16][k = quad*8 + e] -- coalesced 16 B/lane
    short8 qf = *(const short8*)(q_ws + (jbase + js * 16 + n16) * 32 + quad * 8);

    // MFMA + scatter into LDS tile: T[j_local = n16][z = zt*16 + quad*4 + r]
    #pragma unroll
    for (int zt = 0; zt < 8; ++zt) {
      floatx4 acc = cv[zt];   // fold +c_i[z] into accumulator
      acc = __builtin_amdgcn_mfma_f32_16x16x32_bf16(wf[zt], qf, acc, 0, 0, 0);
      *(floatx4*)(twave + n16 * 132 + zt * 16 + quad * 4) = acc;
    }

    // Read back row-contiguous and store: each instr = contiguous 1 KiB/wave.
    // byte offset t*1024 + lane*16  ->  j_local = 2t + (lane>>5), z0 = (lane&31)*4
    float* obase = out + ((size_t)(i * 1024 + jbase + js * 16)) * CZ;
    #pragma unroll
    for (int t = 0; t < 8; ++t) {
      const int jl = 2 * t + (lane >> 5);
      const int z0 = (lane & 31) * 4;
      floatx4 vv = *(const floatx4*)(twave + jl * 132 + z0);
      *(floatx4*)(obase + t * 256 + lane * 4) = vv;
    }
  }
}

extern "C" void kernel_launch(void* const* d_in, const int* in_sizes, int n_in,
                              void* d_out, int out_size, void* d_ws, size_t ws_size,
                              hipStream_t stream) {
  const float* seq = (const float*)d_in[0];
  const float* lnw = (const float*)d_in[1];
  const float* lnb = (const float*)d_in[2];
  const float* pw  = (const float*)d_in[3];
  const float* pb  = (const float*)d_in[4];
  const float* ow  = (const float*)d_in[5];
  const float* ob  = (const float*)d_in[6];
  float* out = (float*)d_out;

  unsigned short* q_ws  = (unsigned short*)d_ws;                         // 1024*32 bf16  = 64 KB
  float*          c_all = (float*)((char*)d_ws + 64 * 1024);             // 1024*128 f32  = 512 KB
  unsigned short* w_all = (unsigned short*)((char*)d_ws + 640 * 1024);   // 1024*128*32 bf16 = 8 MB

  prep_kernel<<<1024, 256, 0, stream>>>(seq, lnw, lnb, pw, pb, ow, ob, q_ws, w_all, c_all);
  pair_kernel<<<4096, 256, 0, stream>>>(q_ws, w_all, c_all, out);
}

// Round 3
// 548.788 us; speedup vs baseline: 1.0536x; 1.0311x over previous
//
#include <hip/hip_runtime.h>

#define CS   1024
#define CZ   128

typedef __attribute__((ext_vector_type(8))) short short8;
typedef __attribute__((ext_vector_type(4))) float floatx4;

static __device__ __forceinline__ unsigned short f2bf(float f) {
  unsigned int u = __float_as_uint(f);
  u = (u + 0x7fffu + ((u >> 16) & 1u)) >> 16;   // round-to-nearest-even
  return (unsigned short)u;
}

// ---------------- Kernel 1: LayerNorm + proj -> q (bf16); expand W_i (bf16), c_i (f32) ----------------
// W_all[i][z][d] = bf16(k[i,d]*ow[z,d] + ow[z,32+d])      (8 MB)
// c_all[i][z]    = ob[z] - sum_d k[i,d]*ow[z,32+d]        (512 KB)
//
// proj mapping (round-3 fix): wave w computes outputs d in [16w, 16w+16);
// LANES SPLIT K -> every pw load instruction is a contiguous 1 KiB wave read.
// (Old mapping had lane = d: 64 lanes at 4 KiB stride = 64 transactions/instr.)
__global__ __launch_bounds__(256) void prep_kernel(
    const float* __restrict__ seq,
    const float* __restrict__ lnw,
    const float* __restrict__ lnb,
    const float* __restrict__ pw,
    const float* __restrict__ pb,
    const float* __restrict__ ow,
    const float* __restrict__ ob,
    unsigned short* __restrict__ q_ws,
    unsigned short* __restrict__ w_all,
    float* __restrict__ c_all) {
  const int row  = blockIdx.x;
  const int tid  = threadIdx.x;
  const int lane = tid & 63;
  const int wave = tid >> 6;

  __shared__ __align__(16) float snf[CS];
  __shared__ float sred[8];
  __shared__ float dout[64];
  __shared__ float ksh[32];

  // each thread owns 4 consecutive elements
  float4 v = *(const float4*)(seq + (size_t)row * CS + tid * 4);
  float s  = v.x + v.y + v.z + v.w;
  float ss = v.x * v.x + v.y * v.y + v.z * v.z + v.w * v.w;
  #pragma unroll
  for (int off = 32; off >= 1; off >>= 1) {
    s  += __shfl_down(s, off, 64);
    ss += __shfl_down(ss, off, 64);
  }
  if (lane == 0) { sred[wave] = s; sred[4 + wave] = ss; }
  __syncthreads();
  const float mu   = (sred[0] + sred[1] + sred[2] + sred[3]) * (1.0f / CS);
  const float var  = (sred[4] + sred[5] + sred[6] + sred[7]) * (1.0f / CS) - mu * mu;
  const float rstd = rsqrtf(var + 1e-5f);
  {
    const int c = tid * 4;
    float4 gw = *(const float4*)(lnw + c);
    float4 gb = *(const float4*)(lnb + c);
    snf[c + 0] = (v.x - mu) * rstd * gw.x + gb.x;
    snf[c + 1] = (v.y - mu) * rstd * gw.y + gb.y;
    snf[c + 2] = (v.z - mu) * rstd * gw.z + gb.z;
    snf[c + 3] = (v.w - mu) * rstd * gw.w + gb.w;
  }
  __syncthreads();

  // ---- proj: coalesced K-split ----
  // lane's K-slice of the normalized row (same for all d): 4 x float4,
  // conflict-free ds_read_b128 (64 lanes x 16 B contiguous per part).
  float4 a0 = *(const float4*)(snf +   0 + lane * 4);
  float4 a1 = *(const float4*)(snf + 256 + lane * 4);
  float4 a2 = *(const float4*)(snf + 512 + lane * 4);
  float4 a3 = *(const float4*)(snf + 768 + lane * 4);

  #pragma unroll 4
  for (int dd = 0; dd < 16; ++dd) {
    const int d = wave * 16 + dd;
    const float* pwr = pw + (size_t)d * CS + lane * 4;
    float4 b0 = *(const float4*)(pwr +   0);   // each: contiguous 1 KiB / wave
    float4 b1 = *(const float4*)(pwr + 256);
    float4 b2 = *(const float4*)(pwr + 512);
    float4 b3 = *(const float4*)(pwr + 768);
    float acc = a0.x * b0.x + a0.y * b0.y + a0.z * b0.z + a0.w * b0.w
              + a1.x * b1.x + a1.y * b1.y + a1.z * b1.z + a1.w * b1.w
              + a2.x * b2.x + a2.y * b2.y + a2.z * b2.z + a2.w * b2.w
              + a3.x * b3.x + a3.y * b3.y + a3.z * b3.z + a3.w * b3.w;
    #pragma unroll
    for (int off = 32; off >= 1; off >>= 1) acc += __shfl_down(acc, off, 64);
    if (lane == 0) dout[d] = acc;
  }
  __syncthreads();

  if (tid < 64) {
    float r = dout[tid] + pb[tid];
    if (tid < 32) q_ws[row * 32 + tid] = f2bf(r);
    else          ksh[tid - 32] = r;
  }
  __syncthreads();

  // ---- expand W_i and c_i (thread: z = tid>>1, half of d-range) ----
  const int z  = tid >> 1;
  const int dh = (tid & 1) << 4;
  const float* owr = ow + z * 64;
  unsigned short wloc[16];
  #pragma unroll
  for (int t4 = 0; t4 < 4; ++t4) {
    const int dd = dh + t4 * 4;
    float4 a = *(const float4*)(owr + dd);
    float4 b = *(const float4*)(owr + 32 + dd);
    wloc[t4 * 4 + 0] = f2bf(ksh[dd + 0] * a.x + b.x);
    wloc[t4 * 4 + 1] = f2bf(ksh[dd + 1] * a.y + b.y);
    wloc[t4 * 4 + 2] = f2bf(ksh[dd + 2] * a.z + b.z);
    wloc[t4 * 4 + 3] = f2bf(ksh[dd + 3] * a.w + b.w);
  }
  unsigned short* wdst = w_all + (size_t)row * 4096 + tid * 16;   // [row][z][d], d contiguous
  *(uint4*)(wdst)     = *(const uint4*)(wloc);
  *(uint4*)(wdst + 8) = *(const uint4*)(wloc + 8);

  if ((tid & 1) == 0) {
    float c = ob[z];
    #pragma unroll
    for (int t4 = 0; t4 < 8; ++t4) {
      const int dd = t4 * 4;
      float4 b = *(const float4*)(owr + 32 + dd);
      c -= ksh[dd + 0] * b.x + ksh[dd + 1] * b.y + ksh[dd + 2] * b.z + ksh[dd + 3] * b.w;
    }
    c_all[row * CZ + z] = c;
  }
}

// ---------------- Kernel 2: out[i,j,z] = q[j,:] . W_i[z,:] + c_i[z] ----------------
// MFMA (A = W_i: M = z, B = q: N = j), then a per-wave LDS transpose so every
// global store instruction is a fully contiguous 1 KiB (64 lanes x dwordx4).
__global__ __launch_bounds__(256, 3) void pair_kernel(
    const unsigned short* __restrict__ q_ws,
    const unsigned short* __restrict__ w_all,
    const float* __restrict__ c_all,
    float* __restrict__ out) {
  const int bid  = blockIdx.x;
  const int i    = bid >> 2;     // k-row index
  const int jt   = bid & 3;      // 256-wide j tile
  const int tid  = threadIdx.x;
  const int lane = tid & 63;
  const int wave = tid >> 6;
  const int quad = lane >> 4;
  const int n16  = lane & 15;

  // Per-wave transpose tile: 16 j-rows x 128 z, stride 132 floats.
  __shared__ __align__(16) float tsh[4][16 * 132];

  // W fragments: wf[zt] holds A[m = z%16][k = quad*8 + e] for z = zt*16 + n16
  const unsigned short* wbase = w_all + (size_t)i * 4096 + n16 * 32 + quad * 8;
  short8 wf[8];
  #pragma unroll
  for (int zt = 0; zt < 8; ++zt) wf[zt] = *(const short8*)(wbase + zt * 512);

  // c fragments: cv[zt] = c_i[zt*16 + quad*4 .. +3]  (matches D-row layout)
  const float* cbase = c_all + i * CZ + quad * 4;
  floatx4 cv[8];
  #pragma unroll
  for (int zt = 0; zt < 8; ++zt) {
    float4 t = *(const float4*)(cbase + zt * 16);
    floatx4 c4; c4[0] = t.x; c4[1] = t.y; c4[2] = t.z; c4[3] = t.w;
    cv[zt] = c4;
  }

  float* twave = &tsh[wave][0];
  const int jbase = jt * 256 + wave * 64;

  #pragma unroll
  for (int js = 0; js < 4; ++js) {
    // B-frag: B[n = j%16][k = quad*8 + e] -- coalesced 16 B/lane
    short8 qf = *(const short8*)(q_ws + (jbase + js * 16 + n16) * 32 + quad * 8);

    // MFMA + scatter into LDS tile: T[j_local = n16][z = zt*16 + quad*4 + r]
    #pragma unroll
    for (int zt = 0; zt < 8; ++zt) {
      floatx4 acc = cv[zt];   // fold +c_i[z] into accumulator
      acc = __builtin_amdgcn_mfma_f32_16x16x32_bf16(wf[zt], qf, acc, 0, 0, 0);
      *(floatx4*)(twave + n16 * 132 + zt * 16 + quad * 4) = acc;
    }

    // Read back row-contiguous and store: each instr = contiguous 1 KiB/wave.
    float* obase = out + ((size_t)(i * 1024 + jbase + js * 16)) * CZ;
    #pragma unroll
    for (int t = 0; t < 8; ++t) {
      const int jl = 2 * t + (lane >> 5);
      const int z0 = (lane & 31) * 4;
      floatx4 vv = *(const floatx4*)(twave + jl * 132 + z0);
      *(floatx4*)(obase + t * 256 + lane * 4) = vv;
    }
  }
}

extern "C" void kernel_launch(void* const* d_in, const int* in_sizes, int n_in,
                              void* d_out, int out_size, void* d_ws, size_t ws_size,
                              hipStream_t stream) {
  const float* seq = (const float*)d_in[0];
  const float* lnw = (const float*)d_in[1];
  const float* lnb = (const float*)d_in[2];
  const float* pw  = (const float*)d_in[3];
  const float* pb  = (const float*)d_in[4];
  const float* ow  = (const float*)d_in[5];
  const float* ob  = (const float*)d_in[6];
  float* out = (float*)d_out;

  unsigned short* q_ws  = (unsigned short*)d_ws;                         // 1024*32 bf16  = 64 KB
  float*          c_all = (float*)((char*)d_ws + 64 * 1024);             // 1024*128 f32  = 512 KB
  unsigned short* w_all = (unsigned short*)((char*)d_ws + 640 * 1024);   // 1024*128*32 bf16 = 8 MB

  prep_kernel<<<1024, 256, 0, stream>>>(seq, lnw, lnb, pw, pb, ow, ob, q_ws, w_all, c_all);
  pair_kernel<<<4096, 256, 0, stream>>>(q_ws, w_all, c_all, out);
}